// Round 1
// baseline (130373.657 us; speedup 1.0000x reference)
//
#include <hip/hip_runtime.h>
#include <hip/hip_cooperative_groups.h>

namespace cg = cooperative_groups;

// Problem constants (B,T,D fixed by setup_inputs)
#define BB_ 16
#define TT_ 2048
#define DD_ 1024
#define GG_ 4096   // 4*D
#define NWG 256
#define NT  256

// Persistent-LSTM design:
//  - 256 wgs x 256 threads, 1 wg/CU, cooperative launch, grid.sync() per time step.
//  - Weights register-resident: wg owns 16 gate columns (j = wg*4+{0..3}, gates i,f,g,o),
//    wave w <-> gate w; lane owns k-slice [16*lane, 16*lane+16) -> 64 float4 per matrix.
//  - Per step: stage h (fp32, 64KB) + x_t (fp32, 64KB) in LDS; each thread computes
//    4-column partial dots (128 FMA per batch); two-stage LDS reduction; wave0 pointwise;
//    h_new -> double-buffered global hbuf (d_ws); fence + grid sync + fence (cross-XCD).
//  - x[t+1] prefetched into LDS before grid.sync to hide in barrier wait.

__device__ __forceinline__ void fma4(float4& a, float s, const float4& w) {
  a.x = fmaf(s, w.x, a.x);
  a.y = fmaf(s, w.y, a.y);
  a.z = fmaf(s, w.z, a.z);
  a.w = fmaf(s, w.w, a.w);
}

__global__ __launch_bounds__(NT, 1) void lstm_persist(
    const float* __restrict__ x, const float* __restrict__ carry,
    const float* __restrict__ Wi, const float* __restrict__ Wh,
    const float* __restrict__ bias,
    float* __restrict__ out, float* __restrict__ carry_out,
    float* __restrict__ hbuf)
{
  __shared__ float sh_h[BB_ * DD_];          // 64 KB   [b][k]
  __shared__ float sh_x[BB_ * DD_];          // 64 KB   [b][k]
  __shared__ float sh_part[4 * 1040];        // 16.25KB [bb][lane][16cols], row pitch 1040 (bank-safe)
  __shared__ float sh_yg[16][16];            // [b][localcol = gate*4+jj]
  __shared__ float sh_bias[16];

  const int tid  = threadIdx.x;
  const int wg   = blockIdx.x;       // 0..255 -> j base = wg*4
  const int w    = tid >> 6;         // wave index == gate index
  const int lane = tid & 63;
  const int k0   = lane << 4;        // 16-wide k slice

  cg::grid_group grid = cg::this_grid();

  // ---- weights -> registers (one-time). col = w*1024 + wg*4 + jj; float4 across jj. ----
  float4 wi_r[16], wh_r[16];
  {
    const float4* Wi4 = (const float4*)Wi;
    const float4* Wh4 = (const float4*)Wh;
    const int cbase = w * 256 + wg;                 // float4 column index
#pragma unroll
    for (int kk = 0; kk < 16; ++kk) {
      wi_r[kk] = Wi4[(size_t)(k0 + kk) * (GG_ / 4) + cbase];
      wh_r[kk] = Wh4[(size_t)(k0 + kk) * (GG_ / 4) + cbase];
    }
  }
  if (tid < 16)
    sh_bias[tid] = bias[(tid >> 2) * DD_ + wg * 4 + (tid & 3)];

  // ---- preload h0 (carry[...,0], stride-2) and x_t=0 into LDS ----
  for (int f = tid; f < BB_ * DD_; f += NT)
    sh_h[f] = carry[(f >> 10) * (DD_ * 2) + (f & 1023) * 2];
  {
    const float4* xx = (const float4*)x;
#pragma unroll
    for (int r = 0; r < 16; ++r) {
      int f4 = r * NT + tid;
      int b = f4 >> 8, k4 = f4 & 255;
      ((float4*)sh_x)[f4] = xx[(size_t)b * (TT_ * DD_ / 4) + k4];
    }
  }

  // cell state lives in wave0 registers: lane = b*4 + jj
  float c_state = 0.f;
  if (tid < 64)
    c_state = carry[(tid >> 2) * (DD_ * 2) + (wg * 4 + (tid & 3)) * 2 + 1];

  __syncthreads();

  float* hb0 = hbuf;
  float* hb1 = hbuf + BB_ * DD_;

  for (int t = 0; t < TT_; ++t) {
    // ======== matvec: 4 batch-groups of 4 ========
#pragma unroll 1
    for (int bg = 0; bg < 4; ++bg) {
#pragma unroll
      for (int bb = 0; bb < 4; ++bb) {
        const int bidx = bg * 4 + bb;
        const float4* h4 = (const float4*)(sh_h + bidx * DD_ + k0);
        const float4* x4 = (const float4*)(sh_x + bidx * DD_ + k0);
        float4 acc = make_float4(0.f, 0.f, 0.f, 0.f);
#pragma unroll
        for (int q = 0; q < 4; ++q) {
          float4 hv = h4[q];
          float4 xv = x4[q];
          fma4(acc, hv.x, wh_r[4*q+0]); fma4(acc, xv.x, wi_r[4*q+0]);
          fma4(acc, hv.y, wh_r[4*q+1]); fma4(acc, xv.y, wi_r[4*q+1]);
          fma4(acc, hv.z, wh_r[4*q+2]); fma4(acc, xv.z, wi_r[4*q+2]);
          fma4(acc, hv.w, wh_r[4*q+3]); fma4(acc, xv.w, wi_r[4*q+3]);
        }
        ((float4*)(sh_part + bb * 1040 + lane * 16))[w] = acc;  // [bb][lane][4w..4w+3]
      }
      __syncthreads();
      // stage 2: tid = bb*64 + lc*4 + sq ; each wave reduces one batch of the group
      {
        const int bb = tid >> 6, lc = (tid >> 2) & 15, sq = tid & 3;
        float s = 0.f;
#pragma unroll
        for (int i = 0; i < 16; ++i)
          s += sh_part[bb * 1040 + (sq * 16 + i) * 16 + lc];
        s += __shfl_xor(s, 1);
        s += __shfl_xor(s, 2);
        if (sq == 0)
          sh_yg[bg * 4 + bb][lc] = s + sh_bias[lc];
      }
      __syncthreads();
    }

    // ======== pointwise: wave0, lane = b*4 + jj ========
    if (tid < 64) {
      const int cb = tid >> 2, jj = tid & 3;
      float gi = sh_yg[cb][jj];
      float gf = sh_yg[cb][4 + jj];
      float gg = sh_yg[cb][8 + jj];
      float go = sh_yg[cb][12 + jj];
      gi = 1.f / (1.f + expf(-gi));
      gf = 1.f / (1.f + expf(-gf));
      gg = tanhf(gg);
      go = 1.f / (1.f + expf(-go));
      c_state = gf * c_state + gi * gg;
      float hn = go * tanhf(c_state);
      out[(size_t)cb * (TT_ * DD_) + (size_t)t * DD_ + wg * 4 + jj] = hn;
      float* hb_nxt = ((t + 1) & 1) ? hb1 : hb0;
      hb_nxt[cb * DD_ + wg * 4 + jj] = hn;
      if (t == TT_ - 1) {
        carry_out[cb * (DD_ * 2) + (wg * 4 + jj) * 2 + 0] = hn;
        carry_out[cb * (DD_ * 2) + (wg * 4 + jj) * 2 + 1] = c_state;
      }
    }
    __threadfence();   // release h_new device-wide before barrier

    // ======== prefetch x[t+1] into LDS (hides in barrier wait) ========
    {
      const int tn = (t + 1 < TT_) ? (t + 1) : t;
      const float4* xx = (const float4*)x;
#pragma unroll
      for (int r = 0; r < 16; ++r) {
        int f4 = r * NT + tid;
        int b = f4 >> 8, k4 = f4 & 255;
        ((float4*)sh_x)[f4] = xx[(size_t)b * (TT_ * DD_ / 4) + (size_t)tn * (DD_ / 4) + k4];
      }
    }

    grid.sync();
    __threadfence();   // acquire: invalidate stale L2 lines for cross-XCD h

    // ======== broadcast-load new h ========
    {
      const float* hb_cur = ((t + 1) & 1) ? hb1 : hb0;
      const float4* hh = (const float4*)hb_cur;
#pragma unroll
      for (int r = 0; r < 16; ++r) {
        int f4 = r * NT + tid;
        ((float4*)sh_h)[f4] = hh[f4];
      }
    }
    __syncthreads();
  }
}

extern "C" void kernel_launch(void* const* d_in, const int* in_sizes, int n_in,
                              void* d_out, int out_size, void* d_ws, size_t ws_size,
                              hipStream_t stream) {
  const float* x     = (const float*)d_in[0];
  const float* carry = (const float*)d_in[1];
  const float* Wi    = (const float*)d_in[2];
  const float* Wh    = (const float*)d_in[3];
  const float* bias  = (const float*)d_in[4];
  float* out       = (float*)d_out;
  float* carry_out = out + (size_t)BB_ * TT_ * DD_;
  float* hbuf      = (float*)d_ws;   // 2 * B*D floats, written before read each step

  void* args[] = {(void*)&x, (void*)&carry, (void*)&Wi, (void*)&Wh, (void*)&bias,
                  (void*)&out, (void*)&carry_out, (void*)&hbuf};
  (void)hipLaunchCooperativeKernel((void*)lstm_persist, dim3(NWG), dim3(NT),
                                   args, 0, stream);
}

// Round 2
// 45661.865 us; speedup vs baseline: 2.8552x; 2.8552x over previous
//
#include <hip/hip_runtime.h>

// Problem constants (B,T,D fixed by setup_inputs)
#define BB_ 16
#define TT_ 2048
#define DD_ 1024
#define GG_ 4096   // 4*D
#define NWG 256
#define NT  256
#define SCOPE_AGENT __HIP_MEMORY_SCOPE_AGENT

// Persistent-LSTM, round 2:
//  - 256 wgs x 256 threads, 1 wg/CU, cooperative launch (co-residency only; NO grid.sync).
//  - Hand-rolled barrier: monotonic global counter, fetch_add(RELEASE, AGENT) arrive,
//    relaxed AGENT spin by thread 0. h exchanged via relaxed AGENT atomics (sc1 ->
//    coherent point), so no buffer_inv/wbl2-heavy fences per step.
//  - Weights register-resident (128 VGPRs of float4). Thread k-slice is 4 strided
//    chunks k = q*256 + lane*4 (+0..3)  -> b128 LDS reads hit all 32 banks (no conflict).
//  - Stage-1 partials: scalar stores into [batch][col][lane] pitch-65 (conflict-free).
//  - out[] stores nontemporal (keeps L2 clean so the release's wbl2 is cheap).

__device__ __forceinline__ void fma4(float4& a, float s, const float4& w) {
  a.x = fmaf(s, w.x, a.x);
  a.y = fmaf(s, w.y, a.y);
  a.z = fmaf(s, w.z, a.z);
  a.w = fmaf(s, w.w, a.w);
}

__device__ __forceinline__ float sigm_f(float v) { return 1.f / (1.f + __expf(-v)); }
__device__ __forceinline__ float tanh_f(float v) { return 1.f - 2.f / (1.f + __expf(2.f * v)); }

__global__ __launch_bounds__(NT, 1) void lstm_persist(
    const float* __restrict__ x, const float* __restrict__ carry,
    const float* __restrict__ Wi, const float* __restrict__ Wh,
    const float* __restrict__ bias,
    float* __restrict__ out, float* __restrict__ carry_out,
    float* __restrict__ hbuf, unsigned* __restrict__ bar)
{
  __shared__ float sh_h[BB_ * DD_];          // 64 KB   [b][k]
  __shared__ float sh_x[BB_ * DD_];          // 64 KB   [b][k]
  __shared__ float sh_part[4 * 1040];        // [bb][col(16), pitch 65][lane]
  __shared__ float sh_yg[16][16];            // [b][localcol = gate*4+jj]
  __shared__ float sh_bias[16];

  const int tid  = threadIdx.x;
  const int wgid = blockIdx.x;       // owns gate columns wgid*4 + {0..3} per gate
  const int w    = tid >> 6;         // wave index == gate index
  const int lane = tid & 63;

  // ---- weights -> registers. Thread rows: k = q*256 + lane*4 + c (q,c in 0..3).
  //      float4 across the 4 owned columns of gate w: f4-col index = w*256 + wgid.
  float4 wi_r[16], wh_r[16];
  {
    const float4* Wi4 = (const float4*)Wi;
    const float4* Wh4 = (const float4*)Wh;
    const int cbase = w * 256 + wgid;
#pragma unroll
    for (int q = 0; q < 4; ++q)
#pragma unroll
      for (int c = 0; c < 4; ++c) {
        const int row = q * 256 + lane * 4 + c;
        wi_r[q * 4 + c] = Wi4[(size_t)row * (GG_ / 4) + cbase];
        wh_r[q * 4 + c] = Wh4[(size_t)row * (GG_ / 4) + cbase];
      }
  }
  if (tid < 16)
    sh_bias[tid] = bias[(tid >> 2) * DD_ + wgid * 4 + (tid & 3)];

  // ---- preload h0 (carry[...,0], stride-2) and x_t=0 into LDS ----
  for (int f = tid; f < BB_ * DD_; f += NT)
    sh_h[f] = carry[(f >> 10) * (DD_ * 2) + (f & 1023) * 2];
  {
    const float4* xx = (const float4*)x;
#pragma unroll
    for (int r = 0; r < 16; ++r) {
      int f4 = r * NT + tid;
      int b = f4 >> 8, k4 = f4 & 255;
      ((float4*)sh_x)[f4] = xx[(size_t)b * (TT_ * DD_ / 4) + k4];
    }
  }

  // cell state lives in wave0 registers: lane = b*4 + jj
  float c_state = 0.f;
  if (tid < 64)
    c_state = carry[(tid >> 2) * (DD_ * 2) + (wgid * 4 + (tid & 3)) * 2 + 1];

  __syncthreads();

  float* hb0 = hbuf;
  float* hb1 = hbuf + BB_ * DD_;

  for (int t = 0; t < TT_; ++t) {
    // ======== matvec: 4 batch-groups of 4 ========
#pragma unroll 1
    for (int bg = 0; bg < 4; ++bg) {
#pragma unroll
      for (int bb = 0; bb < 4; ++bb) {
        const int bidx = bg * 4 + bb;
        const float* hbase = sh_h + bidx * DD_ + lane * 4;
        const float* xbase = sh_x + bidx * DD_ + lane * 4;
        float4 acc = make_float4(0.f, 0.f, 0.f, 0.f);
#pragma unroll
        for (int q = 0; q < 4; ++q) {
          float4 hv = *(const float4*)(hbase + q * 256);
          float4 xv = *(const float4*)(xbase + q * 256);
          fma4(acc, hv.x, wh_r[4*q+0]); fma4(acc, xv.x, wi_r[4*q+0]);
          fma4(acc, hv.y, wh_r[4*q+1]); fma4(acc, xv.y, wi_r[4*q+1]);
          fma4(acc, hv.z, wh_r[4*q+2]); fma4(acc, xv.z, wi_r[4*q+2]);
          fma4(acc, hv.w, wh_r[4*q+3]); fma4(acc, xv.w, wi_r[4*q+3]);
        }
        // scalar conflict-free stores: [bb][col = w*4+c, pitch 65][lane]
        float* pp = sh_part + bb * 1040 + (w * 4) * 65 + lane;
        pp[0]      = acc.x;
        pp[65]     = acc.y;
        pp[130]    = acc.z;
        pp[195]    = acc.w;
      }
      __syncthreads();
      // stage 2: tid = bb*64 + lc*4 + sq ; sum 16 lanes each, combine via shfl
      {
        const int bb2 = tid >> 6, lc = (tid >> 2) & 15, sq = tid & 3;
        const float* pp = sh_part + bb2 * 1040 + lc * 65 + sq * 16;
        float s = 0.f;
#pragma unroll
        for (int i = 0; i < 16; ++i)
          s += pp[i];
        s += __shfl_xor(s, 1);
        s += __shfl_xor(s, 2);
        if (sq == 0)
          sh_yg[bg * 4 + bb2][lc] = s + sh_bias[lc];
      }
      __syncthreads();
    }

    // ======== pointwise: wave0, lane = b*4 + jj ========
    float* hb_nxt = ((t + 1) & 1) ? hb1 : hb0;
    if (tid < 64) {
      const int cb = tid >> 2, jj = tid & 3;
      float gi = sigm_f(sh_yg[cb][jj]);
      float gf = sigm_f(sh_yg[cb][4 + jj]);
      float gg = tanh_f(sh_yg[cb][8 + jj]);
      float go = sigm_f(sh_yg[cb][12 + jj]);
      c_state = gf * c_state + gi * gg;
      float hn = go * tanh_f(c_state);
      __builtin_nontemporal_store(hn, &out[(size_t)cb * (TT_ * DD_) + (size_t)t * DD_ + wgid * 4 + jj]);
      __hip_atomic_store(&hb_nxt[cb * DD_ + wgid * 4 + jj], hn, __ATOMIC_RELAXED, SCOPE_AGENT);
      if (t == TT_ - 1) {
        carry_out[cb * (DD_ * 2) + (wgid * 4 + jj) * 2 + 0] = hn;
        carry_out[cb * (DD_ * 2) + (wgid * 4 + jj) * 2 + 1] = c_state;
      }
    }

    // arrive: release orders this wave's h stores before the counter bump
    if (tid == 0)
      __hip_atomic_fetch_add(bar, 1u, __ATOMIC_RELEASE, SCOPE_AGENT);

    // ======== prefetch x[t+1] into LDS (hides in barrier wait) ========
    {
      const int tn = (t + 1 < TT_) ? (t + 1) : t;
      const float4* xx = (const float4*)x;
#pragma unroll
      for (int r = 0; r < 16; ++r) {
        int f4 = r * NT + tid;
        int b = f4 >> 8, k4 = f4 & 255;
        ((float4*)sh_x)[f4] = xx[(size_t)b * (TT_ * DD_ / 4) + (size_t)tn * (DD_ / 4) + k4];
      }
    }

    // spin: thread 0 only, relaxed agent polls on the monotonic counter
    if (tid == 0) {
      const unsigned target = (unsigned)NWG * (unsigned)(t + 1);
      while (__hip_atomic_load(bar, __ATOMIC_RELAXED, SCOPE_AGENT) < target)
        __builtin_amdgcn_s_sleep(1);
    }
    __syncthreads();

    // ======== all-gather new h (device-coherent loads, straight into LDS) ========
    {
      const unsigned long long* hb8 = (const unsigned long long*)hb_nxt;
      unsigned long long* sh8 = (unsigned long long*)sh_h;
#pragma unroll
      for (int r = 0; r < 32; ++r) {
        int idx = r * NT + tid;
        sh8[idx] = __hip_atomic_load(hb8 + idx, __ATOMIC_RELAXED, SCOPE_AGENT);
      }
    }
    __syncthreads();
  }
}

extern "C" void kernel_launch(void* const* d_in, const int* in_sizes, int n_in,
                              void* d_out, int out_size, void* d_ws, size_t ws_size,
                              hipStream_t stream) {
  const float* x     = (const float*)d_in[0];
  const float* carry = (const float*)d_in[1];
  const float* Wi    = (const float*)d_in[2];
  const float* Wh    = (const float*)d_in[3];
  const float* bias  = (const float*)d_in[4];
  float* out       = (float*)d_out;
  float* carry_out = out + (size_t)BB_ * TT_ * DD_;
  float* hbuf      = (float*)d_ws;   // 2 * B*D floats, written before read each step
  unsigned* bar    = (unsigned*)((char*)d_ws + (size_t)2 * BB_ * DD_ * sizeof(float));

  (void)hipMemsetAsync(bar, 0, sizeof(unsigned), stream);

  void* args[] = {(void*)&x, (void*)&carry, (void*)&Wi, (void*)&Wh, (void*)&bias,
                  (void*)&out, (void*)&carry_out, (void*)&hbuf, (void*)&bar};
  (void)hipLaunchCooperativeKernel((void*)lstm_persist, dim3(NWG), dim3(NT),
                                   args, 0, stream);
}

// Round 3
// 33332.837 us; speedup vs baseline: 3.9113x; 1.3699x over previous
//
#include <hip/hip_runtime.h>

// Problem constants (B,T,D fixed by setup_inputs)
#define BB_ 16
#define TT_ 2048
#define DD_ 1024
#define GG_ 4096   // 4*D
#define NWG 256
#define NT  256
#define SCOPE_AGENT __HIP_MEMORY_SCOPE_AGENT

// Persistent-LSTM, round 3:
//  - 256 wgs x 256 threads, 1 wg/CU, cooperative launch (co-residency only).
//  - Flag-array barrier (NO atomic RMW, no single hot line): wg stores flags[wgid]=t+1
//    (manual s_waitcnt(0) release; h stores are sc1 so no L2 writeback needed).
//    Wave 0 polls all 256 flags, 4 per lane, __all ballot. Waves 1-3 park at s_barrier.
//  - x-part of the matvec precomputed into xacc[16] registers during the barrier
//    shadow (right after x[t+1] prefetch). Critical path = h-part matvec only.
//  - Weights register-resident (128 VGPRs of float4); conflict-free LDS layouts.

__device__ __forceinline__ void fma4(float4& a, float s, const float4& w) {
  a.x = fmaf(s, w.x, a.x);
  a.y = fmaf(s, w.y, a.y);
  a.z = fmaf(s, w.z, a.z);
  a.w = fmaf(s, w.w, a.w);
}

__device__ __forceinline__ float sigm_f(float v) { return 1.f / (1.f + __expf(-v)); }
__device__ __forceinline__ float tanh_f(float v) { return 1.f - 2.f / (1.f + __expf(2.f * v)); }

__global__ __launch_bounds__(NT, 1) void lstm_persist(
    const float* __restrict__ x, const float* __restrict__ carry,
    const float* __restrict__ Wi, const float* __restrict__ Wh,
    const float* __restrict__ bias,
    float* __restrict__ out, float* __restrict__ carry_out,
    float* __restrict__ hbuf, unsigned* __restrict__ flags)
{
  __shared__ float sh_h[BB_ * DD_];          // 64 KB   [b][k]
  __shared__ float sh_x[BB_ * DD_];          // 64 KB   [b][k]
  __shared__ float sh_part[4 * 1040];        // [bb][col(16), pitch 65][lane]
  __shared__ float sh_yg[16][16];            // [b][localcol = gate*4+jj]
  __shared__ float sh_bias[16];

  const int tid  = threadIdx.x;
  const int wgid = blockIdx.x;       // owns gate columns wgid*4 + {0..3} per gate
  const int w    = tid >> 6;         // wave index == gate index
  const int lane = tid & 63;

  // ---- weights -> registers. Thread rows: k = q*256 + lane*4 + c (q,c in 0..3).
  float4 wi_r[16], wh_r[16];
  {
    const float4* Wi4 = (const float4*)Wi;
    const float4* Wh4 = (const float4*)Wh;
    const int cbase = w * 256 + wgid;
#pragma unroll
    for (int q = 0; q < 4; ++q)
#pragma unroll
      for (int c = 0; c < 4; ++c) {
        const int row = q * 256 + lane * 4 + c;
        wi_r[q * 4 + c] = Wi4[(size_t)row * (GG_ / 4) + cbase];
        wh_r[q * 4 + c] = Wh4[(size_t)row * (GG_ / 4) + cbase];
      }
  }
  if (tid < 16)
    sh_bias[tid] = bias[(tid >> 2) * DD_ + wgid * 4 + (tid & 3)];

  // ---- preload h0 (carry[...,0], stride-2) and x_t=0 into LDS ----
  for (int f = tid; f < BB_ * DD_; f += NT)
    sh_h[f] = carry[(f >> 10) * (DD_ * 2) + (f & 1023) * 2];
  {
    const float4* xx = (const float4*)x;
#pragma unroll
    for (int r = 0; r < 16; ++r) {
      int f4 = r * NT + tid;
      int b = f4 >> 8, k4 = f4 & 255;
      ((float4*)sh_x)[f4] = xx[(size_t)b * (TT_ * DD_ / 4) + k4];
    }
  }

  // cell state lives in wave0 registers: lane = b*4 + jj
  float c_state = 0.f;
  if (tid < 64)
    c_state = carry[(tid >> 2) * (DD_ * 2) + (wgid * 4 + (tid & 3)) * 2 + 1];

  __syncthreads();

  // ---- prologue: xacc for t=0 from sh_x ----
  float4 xacc[16];
#pragma unroll
  for (int bidx = 0; bidx < 16; ++bidx) {
    const float* xbase = sh_x + bidx * DD_ + lane * 4;
    float4 a = make_float4(0.f, 0.f, 0.f, 0.f);
#pragma unroll
    for (int q = 0; q < 4; ++q) {
      float4 xv = *(const float4*)(xbase + q * 256);
      fma4(a, xv.x, wi_r[4*q+0]); fma4(a, xv.y, wi_r[4*q+1]);
      fma4(a, xv.z, wi_r[4*q+2]); fma4(a, xv.w, wi_r[4*q+3]);
    }
    xacc[bidx] = a;
  }

  float* hb0 = hbuf;
  float* hb1 = hbuf + BB_ * DD_;

  for (int t = 0; t < TT_; ++t) {
    // ======== h-part matvec (xacc pre-added): 4 batch-groups of 4 ========
#pragma unroll 1
    for (int bg = 0; bg < 4; ++bg) {
#pragma unroll
      for (int bb = 0; bb < 4; ++bb) {
        const int bidx = bg * 4 + bb;
        const float* hbase = sh_h + bidx * DD_ + lane * 4;
        float4 acc = xacc[bidx];
#pragma unroll
        for (int q = 0; q < 4; ++q) {
          float4 hv = *(const float4*)(hbase + q * 256);
          fma4(acc, hv.x, wh_r[4*q+0]);
          fma4(acc, hv.y, wh_r[4*q+1]);
          fma4(acc, hv.z, wh_r[4*q+2]);
          fma4(acc, hv.w, wh_r[4*q+3]);
        }
        float* pp = sh_part + bb * 1040 + (w * 4) * 65 + lane;
        pp[0]   = acc.x;
        pp[65]  = acc.y;
        pp[130] = acc.z;
        pp[195] = acc.w;
      }
      __syncthreads();
      {
        const int bb2 = tid >> 6, lc = (tid >> 2) & 15, sq = tid & 3;
        const float* pp = sh_part + bb2 * 1040 + lc * 65 + sq * 16;
        float s = 0.f;
#pragma unroll
        for (int i = 0; i < 16; ++i)
          s += pp[i];
        s += __shfl_xor(s, 1);
        s += __shfl_xor(s, 2);
        if (sq == 0)
          sh_yg[bg * 4 + bb2][lc] = s + sh_bias[lc];
      }
      __syncthreads();
    }

    // ======== pointwise: wave0, lane = b*4 + jj ========
    float* hb_nxt = ((t + 1) & 1) ? hb1 : hb0;
    if (tid < 64) {
      const int cb = tid >> 2, jj = tid & 3;
      float gi = sigm_f(sh_yg[cb][jj]);
      float gf = sigm_f(sh_yg[cb][4 + jj]);
      float gg = tanh_f(sh_yg[cb][8 + jj]);
      float go = sigm_f(sh_yg[cb][12 + jj]);
      c_state = gf * c_state + gi * gg;
      float hn = go * tanh_f(c_state);
      __builtin_nontemporal_store(hn, &out[(size_t)cb * (TT_ * DD_) + (size_t)t * DD_ + wgid * 4 + jj]);
      __hip_atomic_store(&hb_nxt[cb * DD_ + wgid * 4 + jj], hn, __ATOMIC_RELAXED, SCOPE_AGENT);
      if (t == TT_ - 1) {
        carry_out[cb * (DD_ * 2) + (wgid * 4 + jj) * 2 + 0] = hn;
        carry_out[cb * (DD_ * 2) + (wgid * 4 + jj) * 2 + 1] = c_state;
      }
    }

    if (t + 1 < TT_) {
      // publish: wave0's h stores are sc1; drain them, then relaxed flag store.
      if (tid == 0) {
        __builtin_amdgcn_sched_barrier(0);
        __builtin_amdgcn_s_waitcnt(0);
        __builtin_amdgcn_sched_barrier(0);
        __hip_atomic_store(&flags[wgid], (unsigned)(t + 1), __ATOMIC_RELAXED, SCOPE_AGENT);
      }

      // ======== prefetch x[t+1] into LDS (barrier shadow) ========
      {
        const float4* xx = (const float4*)x;
#pragma unroll
        for (int r = 0; r < 16; ++r) {
          int f4 = r * NT + tid;
          int b = f4 >> 8, k4 = f4 & 255;
          ((float4*)sh_x)[f4] = xx[(size_t)b * (TT_ * DD_ / 4) + (size_t)(t + 1) * (DD_ / 4) + k4];
        }
      }
      __syncthreads();

      // ======== x-part matvec for t+1 (barrier shadow) ========
#pragma unroll
      for (int bidx = 0; bidx < 16; ++bidx) {
        const float* xbase = sh_x + bidx * DD_ + lane * 4;
        float4 a = make_float4(0.f, 0.f, 0.f, 0.f);
#pragma unroll
        for (int q = 0; q < 4; ++q) {
          float4 xv = *(const float4*)(xbase + q * 256);
          fma4(a, xv.x, wi_r[4*q+0]); fma4(a, xv.y, wi_r[4*q+1]);
          fma4(a, xv.z, wi_r[4*q+2]); fma4(a, xv.w, wi_r[4*q+3]);
        }
        xacc[bidx] = a;
      }

      // ======== spin: wave0 polls all 256 flags (4/lane) ========
      if (tid < 64) {
        const unsigned tv = (unsigned)(t + 1);
        for (;;) {
          unsigned f0 = __hip_atomic_load(&flags[lane],       __ATOMIC_RELAXED, SCOPE_AGENT);
          unsigned f1 = __hip_atomic_load(&flags[lane + 64],  __ATOMIC_RELAXED, SCOPE_AGENT);
          unsigned f2 = __hip_atomic_load(&flags[lane + 128], __ATOMIC_RELAXED, SCOPE_AGENT);
          unsigned f3 = __hip_atomic_load(&flags[lane + 192], __ATOMIC_RELAXED, SCOPE_AGENT);
          int ok = (f0 >= tv) && (f1 >= tv) && (f2 >= tv) && (f3 >= tv);
          if (__all(ok)) break;
          __builtin_amdgcn_s_sleep(1);
        }
      }
      __syncthreads();

      // ======== all-gather new h (sc1 loads, straight into LDS) ========
      {
        const unsigned long long* hb8 = (const unsigned long long*)hb_nxt;
        unsigned long long* sh8 = (unsigned long long*)sh_h;
#pragma unroll
        for (int r = 0; r < 32; ++r) {
          int idx = r * NT + tid;
          sh8[idx] = __hip_atomic_load(hb8 + idx, __ATOMIC_RELAXED, SCOPE_AGENT);
        }
      }
      __syncthreads();
    }
  }
}

extern "C" void kernel_launch(void* const* d_in, const int* in_sizes, int n_in,
                              void* d_out, int out_size, void* d_ws, size_t ws_size,
                              hipStream_t stream) {
  const float* x     = (const float*)d_in[0];
  const float* carry = (const float*)d_in[1];
  const float* Wi    = (const float*)d_in[2];
  const float* Wh    = (const float*)d_in[3];
  const float* bias  = (const float*)d_in[4];
  float* out       = (float*)d_out;
  float* carry_out = out + (size_t)BB_ * TT_ * DD_;
  float* hbuf      = (float*)d_ws;   // 2 * B*D floats, written before read each step
  unsigned* flags  = (unsigned*)((char*)d_ws + (size_t)2 * BB_ * DD_ * sizeof(float));

  (void)hipMemsetAsync(flags, 0, NWG * sizeof(unsigned), stream);

  void* args[] = {(void*)&x, (void*)&carry, (void*)&Wi, (void*)&Wh, (void*)&bias,
                  (void*)&out, (void*)&carry_out, (void*)&hbuf, (void*)&flags};
  (void)hipLaunchCooperativeKernel((void*)lstm_persist, dim3(NWG), dim3(NT),
                                   args, 0, stream);
}